// Round 1
// baseline (309.286 us; speedup 1.0000x reference)
//
#include <hip/hip_runtime.h>

typedef float f32x4 __attribute__((ext_vector_type(4)));
typedef __bf16 bf16x8 __attribute__((ext_vector_type(8)));
typedef short s16x8 __attribute__((ext_vector_type(8)));

__device__ __forceinline__ unsigned short f2bf(float f) {
  unsigned u = __builtin_bit_cast(unsigned, f);
  return (unsigned short)((u + 0x7fffu + ((u >> 16) & 1u)) >> 16);
}
__device__ __forceinline__ float bf2f(unsigned short s) {
  unsigned u = ((unsigned)s) << 16;
  return __builtin_bit_cast(float, u);
}

#define LSTR 40  // ushort row stride for LDS staging (80B: 16B-aligned, bank-spread)

// ---------------------------------------------------------------------------
// Kernel A: per-(b,n) Gram matrix G[f,g] = sum_l x[f,l]*x[g,l]
// nch chunks per (b,n); each WG writes a PRIVATE partial (no atomics).
// Double-buffered LDS staging: ONE barrier per K-step, global prefetch in regs.
// ---------------------------------------------------------------------------
__global__ __launch_bounds__(256) void gram_kernel(const float* __restrict__ x,
                                                   float* __restrict__ Gpart,
                                                   int shift, int steps) {
  __shared__ __align__(16) unsigned short xsh[2][64 * LSTR];
  __shared__ __align__(16) unsigned short xsl[2][64 * LSTR];
  const int tid = threadIdx.x;
  const int lane = tid & 63;
  const int wave = tid >> 6;
  const int blk = blockIdx.x;
  const int nchm1 = (1 << shift) - 1;
  const int chunk = blk & nchm1;
  const int bn = blk >> shift;
  const int b = bn >> 2;
  const int m1 = (bn >> 1) & 1;
  const int m2 = bn & 1;
  // staging mapping: thread loads 2 adjacent pixels x 4 channels
  const int px0 = (tid & 15) * 2;
  const int c0 = (tid >> 4) * 4;
  // MFMA fragment mapping
  const int mrow = lane & 15;
  const int k8 = (lane >> 4) * 8;
  const int tr0 = (wave >> 1) * 2;  // row-tile pair
  const int tc0 = (wave & 1) * 2;   // col-tile pair

  f32x4 acc[2][2];
#pragma unroll
  for (int i = 0; i < 2; ++i)
#pragma unroll
    for (int j = 0; j < 2; ++j) acc[i][j] = (f32x4){0.f, 0.f, 0.f, 0.f};

  const int l0base = chunk * steps * 32 + px0;
  auto addr = [&](int ks) {
    int l0 = l0base + ks * 32;        // pixel index within (b,n)
    int hy = l0 >> 7, wx = l0 & 127;
    int y = 2 * hy + m1, xx = 2 * wx + m2;
    return x + ((b * 256 + y) * 256 + xx) * 64 + c0;
  };

  const float* p0 = addr(0);
  f32x4 v0 = *(const f32x4*)p0;
  f32x4 v1 = *(const f32x4*)(p0 + 128);  // next pixel in wx (+2 in xx)
  int pb = 0;

  for (int ks = 0; ks < steps; ++ks) {
    // write current register tile -> LDS buffer pb (bf16 hi/lo split)
#pragma unroll
    for (int i = 0; i < 4; ++i) {
      unsigned short h0 = f2bf(v0[i]), h1 = f2bf(v1[i]);
      unsigned short g0 = f2bf(v0[i] - bf2f(h0)), g1 = f2bf(v1[i] - bf2f(h1));
      *(unsigned*)&xsh[pb][(c0 + i) * LSTR + px0] = (unsigned)h0 | ((unsigned)h1 << 16);
      *(unsigned*)&xsl[pb][(c0 + i) * LSTR + px0] = (unsigned)g0 | ((unsigned)g1 << 16);
    }
    __syncthreads();
    // prefetch next step's globals while this step computes
    if (ks + 1 < steps) {
      const float* pn = addr(ks + 1);
      v0 = *(const f32x4*)pn;
      v1 = *(const f32x4*)(pn + 128);
    }
    s16x8 rh[2], rl[2], qh[2], ql[2];
#pragma unroll
    for (int i = 0; i < 2; ++i) {
      rh[i] = *(const s16x8*)&xsh[pb][(16 * (tr0 + i) + mrow) * LSTR + k8];
      rl[i] = *(const s16x8*)&xsl[pb][(16 * (tr0 + i) + mrow) * LSTR + k8];
      qh[i] = *(const s16x8*)&xsh[pb][(16 * (tc0 + i) + mrow) * LSTR + k8];
      ql[i] = *(const s16x8*)&xsl[pb][(16 * (tc0 + i) + mrow) * LSTR + k8];
    }
#pragma unroll
    for (int i = 0; i < 2; ++i)
#pragma unroll
      for (int j = 0; j < 2; ++j) {
        bf16x8 ah = __builtin_bit_cast(bf16x8, rh[i]);
        bf16x8 al = __builtin_bit_cast(bf16x8, rl[i]);
        bf16x8 bh = __builtin_bit_cast(bf16x8, qh[j]);
        bf16x8 bl = __builtin_bit_cast(bf16x8, ql[j]);
        acc[i][j] = __builtin_amdgcn_mfma_f32_16x16x32_bf16(ah, bh, acc[i][j], 0, 0, 0);
        acc[i][j] = __builtin_amdgcn_mfma_f32_16x16x32_bf16(ah, bl, acc[i][j], 0, 0, 0);
        acc[i][j] = __builtin_amdgcn_mfma_f32_16x16x32_bf16(al, bh, acc[i][j], 0, 0, 0);
      }
    pb ^= 1;
  }
  // private partial slab: no atomics
  float* Gp = Gpart + (((size_t)bn << shift) + chunk) * 4096;
#pragma unroll
  for (int i = 0; i < 2; ++i)
#pragma unroll
    for (int j = 0; j < 2; ++j)
#pragma unroll
      for (int r = 0; r < 4; ++r) {
        int row = 16 * (tr0 + i) + (lane >> 4) * 4 + r;
        int col = 16 * (tc0 + j) + (lane & 15);
        Gp[row * 64 + col] = acc[i][j][r];
      }
}

// ---------------------------------------------------------------------------
// Kernel B: per (b,n): S = temp*Wq^T G Wk; W=softmax(S); F = Wv (W^T Wproj)
// fp32, fully b128-vectorized LDS matmuls; 256-thread softmax; 32 WGs
// ---------------------------------------------------------------------------
// A operand accessed as A[kk][row] (contiguous in row)
__device__ __forceinline__ void mm_colA(const float* Ab, const float* Bb,
                                        float* Dst, float scale, int ti4, int tj4) {
  float acc[4][4] = {};
#pragma unroll 8
  for (int kk = 0; kk < 64; ++kk) {
    f32x4 a = *(const f32x4*)&Ab[kk * 68 + ti4];
    f32x4 b = *(const f32x4*)&Bb[kk * 68 + tj4];
#pragma unroll
    for (int i = 0; i < 4; ++i)
#pragma unroll
      for (int j = 0; j < 4; ++j) acc[i][j] += a[i] * b[j];
  }
#pragma unroll
  for (int i = 0; i < 4; ++i) {
    f32x4 o = {acc[i][0] * scale, acc[i][1] * scale, acc[i][2] * scale, acc[i][3] * scale};
    *(f32x4*)&Dst[(ti4 + i) * 68 + tj4] = o;
  }
}

// A operand accessed as A[row][kk] row-major (contiguous in kk); Dst global ld=64
__device__ __forceinline__ void mm_rowA(const float* Ab, const float* Bb,
                                        float* Dst, int ti4, int tj4) {
  float acc[4][4] = {};
#pragma unroll 2
  for (int kk0 = 0; kk0 < 64; kk0 += 4) {
    f32x4 a4[4], b4[4];
#pragma unroll
    for (int i = 0; i < 4; ++i) a4[i] = *(const f32x4*)&Ab[(ti4 + i) * 68 + kk0];
#pragma unroll
    for (int kx = 0; kx < 4; ++kx) b4[kx] = *(const f32x4*)&Bb[(kk0 + kx) * 68 + tj4];
#pragma unroll
    for (int kx = 0; kx < 4; ++kx)
#pragma unroll
      for (int i = 0; i < 4; ++i)
#pragma unroll
        for (int j = 0; j < 4; ++j) acc[i][j] += a4[i][kx] * b4[kx][j];
  }
#pragma unroll
  for (int i = 0; i < 4; ++i) {
    f32x4 o = {acc[i][0], acc[i][1], acc[i][2], acc[i][3]};
    *(f32x4*)&Dst[(ti4 + i) * 64 + tj4] = o;
  }
}

__device__ __forceinline__ void loadW(float* Bsh, const float* W, int ldw, int off, int tid) {
  for (int i = tid * 4; i < 4096; i += 1024) {
    int r = i >> 6, c = i & 63;
    *(f32x4*)&Bsh[r * 68 + c] = *(const f32x4*)&W[r * ldw + off + c];
  }
}

__global__ __launch_bounds__(256) void fuse_kernel(const float* __restrict__ Gpart,
                                                   const float* __restrict__ Wqkv,
                                                   const float* __restrict__ Wproj,
                                                   float* __restrict__ F, int nch) {
  __shared__ __align__(16) float A[64 * 68];
  __shared__ __align__(16) float B[64 * 68];
  __shared__ __align__(16) float T[64 * 68];
  const int tid = threadIdx.x;
  const int bn = blockIdx.x;
  const int ti4 = (tid >> 4) * 4, tj4 = (tid & 15) * 4;

  // reduce partial Gram slabs -> A ; Wk -> B
  {
    const float* gp = Gpart + (size_t)bn * nch * 4096;
    for (int i = tid * 4; i < 4096; i += 1024) {
      f32x4 s = {0.f, 0.f, 0.f, 0.f};
      for (int p = 0; p < nch; ++p) s += *(const f32x4*)&gp[p * 4096 + i];
      int r = i >> 6, c = i & 63;
      *(f32x4*)&A[r * 68 + c] = s;
      *(f32x4*)&B[r * 68 + c] = *(const f32x4*)&Wqkv[r * 192 + 64 + c];
    }
  }
  __syncthreads();
  // T1[f][d] = sum_g G[f][g] Wk[g][d] ; G symmetric -> read A[kk][row]
  mm_colA(A, B, T, 1.f, ti4, tj4);
  __syncthreads();
  loadW(B, Wqkv, 192, 0, tid);  // Wq
  __syncthreads();
  // S[c][d] = temp * sum_f Wq[f][c] T1[f][d]  -> A
  mm_colA(B, T, A, 0.125f, ti4, tj4);
  __syncthreads();
  // softmax rows of A (over d): 4 lanes per row
  {
    const int row = tid >> 2, q = tid & 3;
    float* Ar = A + row * 68 + q * 16;
    f32x4 v[4];
#pragma unroll
    for (int t = 0; t < 4; ++t) v[t] = *(const f32x4*)&Ar[t * 4];
    float mx = -1e30f;
#pragma unroll
    for (int t = 0; t < 4; ++t)
#pragma unroll
      for (int e = 0; e < 4; ++e) mx = fmaxf(mx, v[t][e]);
    mx = fmaxf(mx, __shfl_xor(mx, 1));
    mx = fmaxf(mx, __shfl_xor(mx, 2));
    float s = 0.f;
#pragma unroll
    for (int t = 0; t < 4; ++t)
#pragma unroll
      for (int e = 0; e < 4; ++e) {
        float ev = __expf(v[t][e] - mx);
        v[t][e] = ev;
        s += ev;
      }
    s += __shfl_xor(s, 1);
    s += __shfl_xor(s, 2);
    float inv = 1.f / s;
#pragma unroll
    for (int t = 0; t < 4; ++t) {
      v[t] *= inv;
      *(f32x4*)&Ar[t * 4] = v[t];
    }
  }
  __syncthreads();
  loadW(B, Wproj, 64, 0, tid);
  __syncthreads();
  // T2[d][e] = sum_c W[c][d] Wproj[c][e]  -> T
  mm_colA(A, B, T, 1.f, ti4, tj4);
  __syncthreads();
  loadW(B, Wqkv, 192, 128, tid);  // Wv
  __syncthreads();
  // F[f][e] = sum_d Wv[f][d] T2[d][e]  -> global
  mm_rowA(B, T, F + bn * 4096, ti4, tj4);
}

// ---------------------------------------------------------------------------
// Kernel C: out[pixel][e] = sum_f x[pixel][f] * F[bn(pixel)][f][e]
// bf16 hi/lo MFMA, A-frags straight from global, B-frags in regs.
// Nontemporal stores: keep x resident in L3 while out streams past it.
// ---------------------------------------------------------------------------
__global__ __launch_bounds__(256) void out_kernel(const float* __restrict__ x,
                                                  const float* __restrict__ F,
                                                  float* __restrict__ out) {
  const int tid = threadIdx.x;
  const int lane = tid & 63;
  const int wave = tid >> 6;
  const int blk = blockIdx.x;
  const int hyg = blk & 63;
  const int bn = blk >> 6;
  const int b = bn >> 2;
  const int m1 = (bn >> 1) & 1;
  const int m2 = bn & 1;

  // B-frags (Wfused), hi/lo
  s16x8 bh[2][4], bl[2][4];
  const float* Fp = F + bn * 4096;
#pragma unroll
  for (int ksj = 0; ksj < 2; ++ksj)
#pragma unroll
    for (int tc = 0; tc < 4; ++tc) {
      s16x8 hv, lv;
#pragma unroll
      for (int j = 0; j < 8; ++j) {
        int k = ksj * 32 + (lane >> 4) * 8 + j;
        int e = tc * 16 + (lane & 15);
        float f = Fp[k * 64 + e];
        unsigned short hb = f2bf(f);
        hv[j] = (short)hb;
        lv[j] = (short)f2bf(f - bf2f(hb));
      }
      bh[ksj][tc] = hv;
      bl[ksj][tc] = lv;
    }

  for (int r = 0; r < 2; ++r) {
    int hy = hyg * 2 + r;
    int y = 2 * hy + m1;
    const float* xrow = x + ((b * 256 + y) * 256) * 64;
    float* orow = out + ((b * 256 + y) * 256) * 64;
#pragma unroll
    for (int ptI = 0; ptI < 2; ++ptI) {
      int pt = wave + ptI * 4;  // px-tile 0..7
      int wx = pt * 16 + (lane & 15);
      int xx = 2 * wx + m2;
      const float* pp = xrow + xx * 64 + (lane >> 4) * 8;
      s16x8 ah[2], al[2];
#pragma unroll
      for (int ksj = 0; ksj < 2; ++ksj) {
        f32x4 u0 = *(const f32x4*)(pp + ksj * 32);
        f32x4 u1 = *(const f32x4*)(pp + ksj * 32 + 4);
        s16x8 hv, lv;
#pragma unroll
        for (int j = 0; j < 4; ++j) {
          unsigned short hb0 = f2bf(u0[j]);
          unsigned short hb1 = f2bf(u1[j]);
          hv[j] = (short)hb0;
          hv[4 + j] = (short)hb1;
          lv[j] = (short)f2bf(u0[j] - bf2f(hb0));
          lv[4 + j] = (short)f2bf(u1[j] - bf2f(hb1));
        }
        ah[ksj] = hv;
        al[ksj] = lv;
      }
      f32x4 acc[4];
#pragma unroll
      for (int tc = 0; tc < 4; ++tc) acc[tc] = (f32x4){0.f, 0.f, 0.f, 0.f};
#pragma unroll
      for (int ksj = 0; ksj < 2; ++ksj)
#pragma unroll
        for (int tc = 0; tc < 4; ++tc) {
          bf16x8 A_h = __builtin_bit_cast(bf16x8, ah[ksj]);
          bf16x8 A_l = __builtin_bit_cast(bf16x8, al[ksj]);
          bf16x8 B_h = __builtin_bit_cast(bf16x8, bh[ksj][tc]);
          bf16x8 B_l = __builtin_bit_cast(bf16x8, bl[ksj][tc]);
          acc[tc] = __builtin_amdgcn_mfma_f32_16x16x32_bf16(A_h, B_h, acc[tc], 0, 0, 0);
          acc[tc] = __builtin_amdgcn_mfma_f32_16x16x32_bf16(A_h, B_l, acc[tc], 0, 0, 0);
          acc[tc] = __builtin_amdgcn_mfma_f32_16x16x32_bf16(A_l, B_h, acc[tc], 0, 0, 0);
        }
#pragma unroll
      for (int tc = 0; tc < 4; ++tc)
#pragma unroll
        for (int j = 0; j < 4; ++j) {
          int prow = (lane >> 4) * 4 + j;
          int xx2 = 2 * (pt * 16 + prow) + m2;
          __builtin_nontemporal_store(acc[tc][j], &orow[xx2 * 64 + tc * 16 + (lane & 15)]);
        }
    }
  }
}

extern "C" void kernel_launch(void* const* d_in, const int* in_sizes, int n_in,
                              void* d_out, int out_size, void* d_ws, size_t ws_size,
                              hipStream_t stream) {
  (void)in_sizes; (void)n_in; (void)out_size;
  const float* x = (const float*)d_in[0];
  const float* Wqkv = (const float*)d_in[1];
  const float* Wproj = (const float*)d_in[2];
  float* out = (float*)d_out;

  // choose chunk count so workspace fits: Gpart = 32*nch*4096 f32, F = 32*4096 f32
  int shift = 5;  // nch = 32
  while (shift > 0) {
    size_t need = ((32ull << shift) + 32ull) * 4096ull * 4ull;
    if (need <= ws_size) break;
    --shift;
  }
  const int nch = 1 << shift;
  const int steps = 512 >> shift;  // K-steps of 32 pixels per chunk

  float* Gpart = (float*)d_ws;
  float* F = Gpart + ((size_t)32 << shift) * 4096;

  gram_kernel<<<32 * nch, 256, 0, stream>>>(x, Gpart, shift, steps);
  fuse_kernel<<<32, 256, 0, stream>>>(Gpart, Wqkv, Wproj, F, nch);
  out_kernel<<<2048, 256, 0, stream>>>(x, F, out);
}

// Round 2
// 288.555 us; speedup vs baseline: 1.0718x; 1.0718x over previous
//
#include <hip/hip_runtime.h>

typedef float f32x4 __attribute__((ext_vector_type(4)));
typedef __bf16 bf16x8 __attribute__((ext_vector_type(8)));
typedef short s16x8 __attribute__((ext_vector_type(8)));

__device__ __forceinline__ unsigned short f2bf(float f) {
  unsigned u = __builtin_bit_cast(unsigned, f);
  return (unsigned short)((u + 0x7fffu + ((u >> 16) & 1u)) >> 16);
}
__device__ __forceinline__ float bf2f(unsigned short s) {
  unsigned u = ((unsigned)s) << 16;
  return __builtin_bit_cast(float, u);
}

#define LSTR 40  // ushort row stride for LDS staging (80B: 16B-aligned, bank-spread)

// ---------------------------------------------------------------------------
// Kernel A: per-(b,n) Gram matrix partials G[f,g] = sum_l x[f,l]*x[g,l]
// nch chunks per (b,n); each WG writes a PRIVATE partial slab (no atomics).
// Double-buffered LDS staging: ONE barrier per K-step, global prefetch in regs.
// Epilogue: G symmetric -> store transposed tile as f32x4 (4 stores/thread).
// ---------------------------------------------------------------------------
__global__ __launch_bounds__(256) void gram_kernel(const float* __restrict__ x,
                                                   float* __restrict__ Gpart,
                                                   int shift, int steps) {
  __shared__ __align__(16) unsigned short xsh[2][64 * LSTR];
  __shared__ __align__(16) unsigned short xsl[2][64 * LSTR];
  const int tid = threadIdx.x;
  const int lane = tid & 63;
  const int wave = tid >> 6;
  const int blk = blockIdx.x;
  const int nchm1 = (1 << shift) - 1;
  const int chunk = blk & nchm1;
  const int bn = blk >> shift;
  const int b = bn >> 2;
  const int m1 = (bn >> 1) & 1;
  const int m2 = bn & 1;
  // staging mapping: thread loads 2 adjacent pixels x 4 channels
  const int px0 = (tid & 15) * 2;
  const int c0 = (tid >> 4) * 4;
  // MFMA fragment mapping
  const int mrow = lane & 15;
  const int k8 = (lane >> 4) * 8;
  const int tr0 = (wave >> 1) * 2;  // row-tile pair
  const int tc0 = (wave & 1) * 2;   // col-tile pair

  f32x4 acc[2][2];
#pragma unroll
  for (int i = 0; i < 2; ++i)
#pragma unroll
    for (int j = 0; j < 2; ++j) acc[i][j] = (f32x4){0.f, 0.f, 0.f, 0.f};

  const int l0base = chunk * steps * 32 + px0;
  auto addr = [&](int ks) {
    int l0 = l0base + ks * 32;        // pixel index within (b,n)
    int hy = l0 >> 7, wx = l0 & 127;
    int y = 2 * hy + m1, xx = 2 * wx + m2;
    return x + ((b * 256 + y) * 256 + xx) * 64 + c0;
  };

  const float* p0 = addr(0);
  f32x4 v0 = *(const f32x4*)p0;
  f32x4 v1 = *(const f32x4*)(p0 + 128);  // next pixel in wx (+2 in xx)
  int pb = 0;

  for (int ks = 0; ks < steps; ++ks) {
    // write current register tile -> LDS buffer pb (bf16 hi/lo split)
#pragma unroll
    for (int i = 0; i < 4; ++i) {
      unsigned short h0 = f2bf(v0[i]), h1 = f2bf(v1[i]);
      unsigned short g0 = f2bf(v0[i] - bf2f(h0)), g1 = f2bf(v1[i] - bf2f(h1));
      *(unsigned*)&xsh[pb][(c0 + i) * LSTR + px0] = (unsigned)h0 | ((unsigned)h1 << 16);
      *(unsigned*)&xsl[pb][(c0 + i) * LSTR + px0] = (unsigned)g0 | ((unsigned)g1 << 16);
    }
    __syncthreads();
    // prefetch next step's globals while this step computes
    if (ks + 1 < steps) {
      const float* pn = addr(ks + 1);
      v0 = *(const f32x4*)pn;
      v1 = *(const f32x4*)(pn + 128);
    }
    s16x8 rh[2], rl[2], qh[2], ql[2];
#pragma unroll
    for (int i = 0; i < 2; ++i) {
      rh[i] = *(const s16x8*)&xsh[pb][(16 * (tr0 + i) + mrow) * LSTR + k8];
      rl[i] = *(const s16x8*)&xsl[pb][(16 * (tr0 + i) + mrow) * LSTR + k8];
      qh[i] = *(const s16x8*)&xsh[pb][(16 * (tc0 + i) + mrow) * LSTR + k8];
      ql[i] = *(const s16x8*)&xsl[pb][(16 * (tc0 + i) + mrow) * LSTR + k8];
    }
#pragma unroll
    for (int i = 0; i < 2; ++i)
#pragma unroll
      for (int j = 0; j < 2; ++j) {
        bf16x8 ah = __builtin_bit_cast(bf16x8, rh[i]);
        bf16x8 al = __builtin_bit_cast(bf16x8, rl[i]);
        bf16x8 bh = __builtin_bit_cast(bf16x8, qh[j]);
        bf16x8 bl = __builtin_bit_cast(bf16x8, ql[j]);
        acc[i][j] = __builtin_amdgcn_mfma_f32_16x16x32_bf16(ah, bh, acc[i][j], 0, 0, 0);
        acc[i][j] = __builtin_amdgcn_mfma_f32_16x16x32_bf16(ah, bl, acc[i][j], 0, 0, 0);
        acc[i][j] = __builtin_amdgcn_mfma_f32_16x16x32_bf16(al, bh, acc[i][j], 0, 0, 0);
      }
    pb ^= 1;
  }
  // private partial slab; G symmetric -> write transposed tile, vectorized
  float* Gp = Gpart + (((size_t)bn << shift) + chunk) * 4096;
  const int rowb = (lane >> 4) * 4;
#pragma unroll
  for (int i = 0; i < 2; ++i)
#pragma unroll
    for (int j = 0; j < 2; ++j) {
      int col = 16 * (tc0 + j) + (lane & 15);
      int row0 = 16 * (tr0 + i) + rowb;
      *(f32x4*)&Gp[col * 64 + row0] = acc[i][j];
    }
}

// ---------------------------------------------------------------------------
// Kernel A2: reduce partial slabs -> compact G (full-device parallel)
// ---------------------------------------------------------------------------
__global__ __launch_bounds__(256) void reduce_kernel(const float* __restrict__ Gpart,
                                                     float* __restrict__ G, int nch) {
  const int gid = blockIdx.x * 256 + threadIdx.x;  // one f32x4 per thread
  const int i4 = gid * 4;                          // 0..131071
  const int bn = i4 >> 12;
  const int idx = i4 & 4095;
  const float* gp = Gpart + ((size_t)bn * nch) * 4096 + idx;
  f32x4 s = {0.f, 0.f, 0.f, 0.f};
#pragma unroll 8
  for (int p = 0; p < nch; ++p) s += *(const f32x4*)&gp[(size_t)p * 4096];
  *(f32x4*)&G[i4] = s;
}

// ---------------------------------------------------------------------------
// Kernel B: per (b,n): S = temp*Wq^T G Wk; W=softmax(S); F = Wv (W^T Wproj)
// fp32, fully b128-vectorized LDS matmuls; 256-thread softmax; 32 WGs
// ---------------------------------------------------------------------------
// A operand accessed as A[kk][row] (contiguous in row)
__device__ __forceinline__ void mm_colA(const float* Ab, const float* Bb,
                                        float* Dst, float scale, int ti4, int tj4) {
  float acc[4][4] = {};
#pragma unroll 8
  for (int kk = 0; kk < 64; ++kk) {
    f32x4 a = *(const f32x4*)&Ab[kk * 68 + ti4];
    f32x4 b = *(const f32x4*)&Bb[kk * 68 + tj4];
#pragma unroll
    for (int i = 0; i < 4; ++i)
#pragma unroll
      for (int j = 0; j < 4; ++j) acc[i][j] += a[i] * b[j];
  }
#pragma unroll
  for (int i = 0; i < 4; ++i) {
    f32x4 o = {acc[i][0] * scale, acc[i][1] * scale, acc[i][2] * scale, acc[i][3] * scale};
    *(f32x4*)&Dst[(ti4 + i) * 68 + tj4] = o;
  }
}

// A operand accessed as A[row][kk] row-major (contiguous in kk); Dst global ld=64
__device__ __forceinline__ void mm_rowA(const float* Ab, const float* Bb,
                                        float* Dst, int ti4, int tj4) {
  float acc[4][4] = {};
#pragma unroll 2
  for (int kk0 = 0; kk0 < 64; kk0 += 4) {
    f32x4 a4[4], b4[4];
#pragma unroll
    for (int i = 0; i < 4; ++i) a4[i] = *(const f32x4*)&Ab[(ti4 + i) * 68 + kk0];
#pragma unroll
    for (int kx = 0; kx < 4; ++kx) b4[kx] = *(const f32x4*)&Bb[(kk0 + kx) * 68 + tj4];
#pragma unroll
    for (int kx = 0; kx < 4; ++kx)
#pragma unroll
      for (int i = 0; i < 4; ++i)
#pragma unroll
        for (int j = 0; j < 4; ++j) acc[i][j] += a4[i][kx] * b4[kx][j];
  }
#pragma unroll
  for (int i = 0; i < 4; ++i) {
    f32x4 o = {acc[i][0], acc[i][1], acc[i][2], acc[i][3]};
    *(f32x4*)&Dst[(ti4 + i) * 64 + tj4] = o;
  }
}

__device__ __forceinline__ void loadW(float* Bsh, const float* W, int ldw, int off, int tid) {
  for (int i = tid * 4; i < 4096; i += 1024) {
    int r = i >> 6, c = i & 63;
    *(f32x4*)&Bsh[r * 68 + c] = *(const f32x4*)&W[r * ldw + off + c];
  }
}

__global__ __launch_bounds__(256) void fuse_kernel(const float* __restrict__ G,
                                                   const float* __restrict__ Wqkv,
                                                   const float* __restrict__ Wproj,
                                                   float* __restrict__ F) {
  __shared__ __align__(16) float A[64 * 68];
  __shared__ __align__(16) float B[64 * 68];
  __shared__ __align__(16) float T[64 * 68];
  const int tid = threadIdx.x;
  const int bn = blockIdx.x;
  const int ti4 = (tid >> 4) * 4, tj4 = (tid & 15) * 4;

  // load compact G -> A ; Wk -> B (both vectorized)
  for (int i = tid * 4; i < 4096; i += 1024) {
    int r = i >> 6, c = i & 63;
    *(f32x4*)&A[r * 68 + c] = *(const f32x4*)&G[bn * 4096 + i];
    *(f32x4*)&B[r * 68 + c] = *(const f32x4*)&Wqkv[r * 192 + 64 + c];
  }
  __syncthreads();
  // T1[f][d] = sum_g G[f][g] Wk[g][d] ; G symmetric -> read A[kk][row]
  mm_colA(A, B, T, 1.f, ti4, tj4);
  __syncthreads();
  loadW(B, Wqkv, 192, 0, tid);  // Wq
  __syncthreads();
  // S[c][d] = temp * sum_f Wq[f][c] T1[f][d]  -> A
  mm_colA(B, T, A, 0.125f, ti4, tj4);
  __syncthreads();
  // softmax rows of A (over d): 4 lanes per row
  {
    const int row = tid >> 2, q = tid & 3;
    float* Ar = A + row * 68 + q * 16;
    f32x4 v[4];
#pragma unroll
    for (int t = 0; t < 4; ++t) v[t] = *(const f32x4*)&Ar[t * 4];
    float mx = -1e30f;
#pragma unroll
    for (int t = 0; t < 4; ++t)
#pragma unroll
      for (int e = 0; e < 4; ++e) mx = fmaxf(mx, v[t][e]);
    mx = fmaxf(mx, __shfl_xor(mx, 1));
    mx = fmaxf(mx, __shfl_xor(mx, 2));
    float s = 0.f;
#pragma unroll
    for (int t = 0; t < 4; ++t)
#pragma unroll
      for (int e = 0; e < 4; ++e) {
        float ev = __expf(v[t][e] - mx);
        v[t][e] = ev;
        s += ev;
      }
    s += __shfl_xor(s, 1);
    s += __shfl_xor(s, 2);
    float inv = 1.f / s;
#pragma unroll
    for (int t = 0; t < 4; ++t) {
      v[t] *= inv;
      *(f32x4*)&Ar[t * 4] = v[t];
    }
  }
  __syncthreads();
  loadW(B, Wproj, 64, 0, tid);
  __syncthreads();
  // T2[d][e] = sum_c W[c][d] Wproj[c][e]  -> T
  mm_colA(A, B, T, 1.f, ti4, tj4);
  __syncthreads();
  loadW(B, Wqkv, 192, 128, tid);  // Wv
  __syncthreads();
  // F[f][e] = sum_d Wv[f][d] T2[d][e]  -> global
  mm_rowA(B, T, F + bn * 4096, ti4, tj4);
}

// ---------------------------------------------------------------------------
// Kernel C: out[pixel][e] = sum_f x[pixel][f] * F[bn(pixel)][f][e]
// bf16 hi/lo MFMA. Operand-swapped: D[e][pixel] so each lane holds 4
// consecutive output channels -> f32x4 nontemporal stores (4x fewer VMEM).
// A/B fragment lane layouts are symmetric, so register images unchanged.
// ---------------------------------------------------------------------------
__global__ __launch_bounds__(256) void out_kernel(const float* __restrict__ x,
                                                  const float* __restrict__ F,
                                                  float* __restrict__ out) {
  const int tid = threadIdx.x;
  const int lane = tid & 63;
  const int wave = tid >> 6;
  const int blk = blockIdx.x;
  const int hyg = blk & 63;
  const int bn = blk >> 6;
  const int b = bn >> 2;
  const int m1 = (bn >> 1) & 1;
  const int m2 = bn & 1;

  // F-frags, hi/lo: element F[k][e], lane layout valid as A-operand (rows=e)
  s16x8 bh[2][4], bl[2][4];
  const float* Fp = F + bn * 4096;
#pragma unroll
  for (int ksj = 0; ksj < 2; ++ksj)
#pragma unroll
    for (int tc = 0; tc < 4; ++tc) {
      s16x8 hv, lv;
#pragma unroll
      for (int j = 0; j < 8; ++j) {
        int k = ksj * 32 + (lane >> 4) * 8 + j;
        int e = tc * 16 + (lane & 15);
        float f = Fp[k * 64 + e];
        unsigned short hb = f2bf(f);
        hv[j] = (short)hb;
        lv[j] = (short)f2bf(f - bf2f(hb));
      }
      bh[ksj][tc] = hv;
      bl[ksj][tc] = lv;
    }

  const int e4 = (lane >> 4) * 4;  // acc rows: 4 consecutive e within tc-tile

  for (int r = 0; r < 2; ++r) {
    int hy = hyg * 2 + r;
    int y = 2 * hy + m1;
    const float* xrow = x + ((b * 256 + y) * 256) * 64;
    float* orow = out + ((b * 256 + y) * 256) * 64;
#pragma unroll
    for (int ptI = 0; ptI < 2; ++ptI) {
      int pt = wave + ptI * 4;  // px-tile 0..7
      int wx = pt * 16 + (lane & 15);
      int xx = 2 * wx + m2;
      const float* pp = xrow + xx * 64 + (lane >> 4) * 8;
      s16x8 ah[2], al[2];
#pragma unroll
      for (int ksj = 0; ksj < 2; ++ksj) {
        f32x4 u0 = *(const f32x4*)(pp + ksj * 32);
        f32x4 u1 = *(const f32x4*)(pp + ksj * 32 + 4);
        s16x8 hv, lv;
#pragma unroll
        for (int j = 0; j < 4; ++j) {
          unsigned short hb0 = f2bf(u0[j]);
          unsigned short hb1 = f2bf(u1[j]);
          hv[j] = (short)hb0;
          hv[4 + j] = (short)hb1;
          lv[j] = (short)f2bf(u0[j] - bf2f(hb0));
          lv[4 + j] = (short)f2bf(u1[j] - bf2f(hb1));
        }
        ah[ksj] = hv;
        al[ksj] = lv;
      }
      f32x4 acc[4];
#pragma unroll
      for (int tc = 0; tc < 4; ++tc) acc[tc] = (f32x4){0.f, 0.f, 0.f, 0.f};
#pragma unroll
      for (int ksj = 0; ksj < 2; ++ksj)
#pragma unroll
        for (int tc = 0; tc < 4; ++tc) {
          bf16x8 A_h = __builtin_bit_cast(bf16x8, ah[ksj]);
          bf16x8 A_l = __builtin_bit_cast(bf16x8, al[ksj]);
          bf16x8 B_h = __builtin_bit_cast(bf16x8, bh[ksj][tc]);
          bf16x8 B_l = __builtin_bit_cast(bf16x8, bl[ksj][tc]);
          // swapped: D[row=e][col=pixel]
          acc[tc] = __builtin_amdgcn_mfma_f32_16x16x32_bf16(B_h, A_h, acc[tc], 0, 0, 0);
          acc[tc] = __builtin_amdgcn_mfma_f32_16x16x32_bf16(B_l, A_h, acc[tc], 0, 0, 0);
          acc[tc] = __builtin_amdgcn_mfma_f32_16x16x32_bf16(B_h, A_l, acc[tc], 0, 0, 0);
        }
      // lane's column = its own wx; rows = e = tc*16 + e4 + 0..3
      float* op = orow + xx * 64;
#pragma unroll
      for (int tc = 0; tc < 4; ++tc) {
        __builtin_nontemporal_store(acc[tc], (f32x4*)&op[tc * 16 + e4]);
      }
    }
  }
}

extern "C" void kernel_launch(void* const* d_in, const int* in_sizes, int n_in,
                              void* d_out, int out_size, void* d_ws, size_t ws_size,
                              hipStream_t stream) {
  (void)in_sizes; (void)n_in; (void)out_size;
  const float* x = (const float*)d_in[0];
  const float* Wqkv = (const float*)d_in[1];
  const float* Wproj = (const float*)d_in[2];
  float* out = (float*)d_out;

  // workspace: Gpart = 32*nch*4096 f32, G = 32*4096 f32, F = 32*4096 f32
  int shift = 5;  // nch = 32
  while (shift > 0) {
    size_t need = ((32ull << shift) + 64ull) * 4096ull * 4ull;
    if (need <= ws_size) break;
    --shift;
  }
  const int nch = 1 << shift;
  const int steps = 512 >> shift;  // K-steps of 32 pixels per chunk

  float* Gpart = (float*)d_ws;
  float* G = Gpart + ((size_t)32 << shift) * 4096;
  float* F = G + 32 * 4096;

  gram_kernel<<<32 * nch, 256, 0, stream>>>(x, Gpart, shift, steps);
  reduce_kernel<<<128, 256, 0, stream>>>(Gpart, G, nch);
  fuse_kernel<<<32, 256, 0, stream>>>(G, Wqkv, Wproj, F);
  out_kernel<<<2048, 256, 0, stream>>>(x, F, out);
}

// Round 3
// 286.824 us; speedup vs baseline: 1.0783x; 1.0060x over previous
//
#include <hip/hip_runtime.h>

typedef float f32x2 __attribute__((ext_vector_type(2)));
typedef float f32x4 __attribute__((ext_vector_type(4)));
typedef __bf16 bf16x8 __attribute__((ext_vector_type(8)));
typedef short s16x8 __attribute__((ext_vector_type(8)));
typedef unsigned short u16x4 __attribute__((ext_vector_type(4)));

__device__ __forceinline__ unsigned short f2bf(float f) {
  unsigned u = __builtin_bit_cast(unsigned, f);
  return (unsigned short)((u + 0x7fffu + ((u >> 16) & 1u)) >> 16);
}
__device__ __forceinline__ float bf2f(unsigned short s) {
  unsigned u = ((unsigned)s) << 16;
  return __builtin_bit_cast(float, u);
}

#define LSTR 40  // ushort row stride for LDS staging (80B: 16B-aligned, bank-spread)
#define NCH 32   // split-K chunks per (b,n)
#define GSTEPS 16

// ---------------------------------------------------------------------------
// Kernel A: per-(b,n) Gram matrix partials G[f,g] = sum_l x[f,l]*x[g,l]
// 32 chunks per (b,n); each WG writes a PRIVATE partial slab (no atomics).
// Double-buffered LDS staging: ONE barrier per K-step, global prefetch in regs.
// Epilogue: G symmetric -> store transposed tile as f32x4 (4 stores/thread).
// ---------------------------------------------------------------------------
__global__ __launch_bounds__(256) void gram_kernel(const float* __restrict__ x,
                                                   float* __restrict__ Gpart) {
  __shared__ __align__(16) unsigned short xsh[2][64 * LSTR];
  __shared__ __align__(16) unsigned short xsl[2][64 * LSTR];
  const int tid = threadIdx.x;
  const int lane = tid & 63;
  const int wave = tid >> 6;
  const int blk = blockIdx.x;
  const int chunk = blk & (NCH - 1);
  const int bn = blk >> 5;
  const int b = bn >> 2;
  const int m1 = (bn >> 1) & 1;
  const int m2 = bn & 1;
  // staging mapping: thread loads 2 adjacent pixels x 4 channels
  const int px0 = (tid & 15) * 2;
  const int c0 = (tid >> 4) * 4;
  // MFMA fragment mapping
  const int mrow = lane & 15;
  const int k8 = (lane >> 4) * 8;
  const int tr0 = (wave >> 1) * 2;  // row-tile pair
  const int tc0 = (wave & 1) * 2;   // col-tile pair

  f32x4 acc[2][2];
#pragma unroll
  for (int i = 0; i < 2; ++i)
#pragma unroll
    for (int j = 0; j < 2; ++j) acc[i][j] = (f32x4){0.f, 0.f, 0.f, 0.f};

  const int l0base = chunk * (GSTEPS * 32) + px0;
  auto addr = [&](int ks) {
    int l0 = l0base + ks * 32;        // pixel index within (b,n)
    int hy = l0 >> 7, wx = l0 & 127;
    int y = 2 * hy + m1, xx = 2 * wx + m2;
    return x + ((b * 256 + y) * 256 + xx) * 64 + c0;
  };

  const float* p0 = addr(0);
  f32x4 v0 = *(const f32x4*)p0;
  f32x4 v1 = *(const f32x4*)(p0 + 128);  // next pixel in wx (+2 in xx)
  int pb = 0;

  for (int ks = 0; ks < GSTEPS; ++ks) {
    // write current register tile -> LDS buffer pb (bf16 hi/lo split)
#pragma unroll
    for (int i = 0; i < 4; ++i) {
      unsigned short h0 = f2bf(v0[i]), h1 = f2bf(v1[i]);
      unsigned short g0 = f2bf(v0[i] - bf2f(h0)), g1 = f2bf(v1[i] - bf2f(h1));
      *(unsigned*)&xsh[pb][(c0 + i) * LSTR + px0] = (unsigned)h0 | ((unsigned)h1 << 16);
      *(unsigned*)&xsl[pb][(c0 + i) * LSTR + px0] = (unsigned)g0 | ((unsigned)g1 << 16);
    }
    __syncthreads();
    // prefetch next step's globals while this step computes
    if (ks + 1 < GSTEPS) {
      const float* pn = addr(ks + 1);
      v0 = *(const f32x4*)pn;
      v1 = *(const f32x4*)(pn + 128);
    }
    s16x8 rh[2], rl[2], qh[2], ql[2];
#pragma unroll
    for (int i = 0; i < 2; ++i) {
      rh[i] = *(const s16x8*)&xsh[pb][(16 * (tr0 + i) + mrow) * LSTR + k8];
      rl[i] = *(const s16x8*)&xsl[pb][(16 * (tr0 + i) + mrow) * LSTR + k8];
      qh[i] = *(const s16x8*)&xsh[pb][(16 * (tc0 + i) + mrow) * LSTR + k8];
      ql[i] = *(const s16x8*)&xsl[pb][(16 * (tc0 + i) + mrow) * LSTR + k8];
    }
#pragma unroll
    for (int i = 0; i < 2; ++i)
#pragma unroll
      for (int j = 0; j < 2; ++j) {
        bf16x8 ah = __builtin_bit_cast(bf16x8, rh[i]);
        bf16x8 al = __builtin_bit_cast(bf16x8, rl[i]);
        bf16x8 bh = __builtin_bit_cast(bf16x8, qh[j]);
        bf16x8 bl = __builtin_bit_cast(bf16x8, ql[j]);
        acc[i][j] = __builtin_amdgcn_mfma_f32_16x16x32_bf16(ah, bh, acc[i][j], 0, 0, 0);
        acc[i][j] = __builtin_amdgcn_mfma_f32_16x16x32_bf16(ah, bl, acc[i][j], 0, 0, 0);
        acc[i][j] = __builtin_amdgcn_mfma_f32_16x16x32_bf16(al, bh, acc[i][j], 0, 0, 0);
      }
    pb ^= 1;
  }
  // private partial slab; G symmetric -> write transposed tile, vectorized
  float* Gp = Gpart + (((size_t)bn << 5) + chunk) * 4096;
  const int rowb = (lane >> 4) * 4;
#pragma unroll
  for (int i = 0; i < 2; ++i)
#pragma unroll
    for (int j = 0; j < 2; ++j) {
      int col = 16 * (tc0 + j) + (lane & 15);
      int row0 = 16 * (tr0 + i) + rowb;
      *(f32x4*)&Gp[col * 64 + row0] = acc[i][j];
    }
}

// ---------------------------------------------------------------------------
// Kernel A2: reduce partial slabs -> compact G. 256 WGs (one per CU), f32x2.
// ---------------------------------------------------------------------------
__global__ __launch_bounds__(256) void reduce_kernel(const float* __restrict__ Gpart,
                                                     float* __restrict__ G) {
  const int gid = blockIdx.x * 256 + threadIdx.x;  // one f32x2 per thread
  const int i2 = gid * 2;                          // 0..131070
  const int bn = i2 >> 12;
  const int idx = i2 & 4095;
  const float* gp = Gpart + ((size_t)bn * NCH) * 4096 + idx;
  f32x2 s = {0.f, 0.f};
#pragma unroll
  for (int p = 0; p < NCH; ++p) s += *(const f32x2*)&gp[(size_t)p * 4096];
  *(f32x2*)&G[i2] = s;
}

// ---------------------------------------------------------------------------
// Kernel B: per (b,n): S = temp*Wq^T G Wk; W=softmax(S); F = Wv (W^T Wproj)
// fp32, fully b128-vectorized LDS matmuls; 256-thread softmax; 32 WGs.
// Emits F pre-transposed + pre-converted to bf16 hi/lo planes Ft[e][f].
// ---------------------------------------------------------------------------
// A operand accessed as A[kk][row] (contiguous in row)
__device__ __forceinline__ void mm_colA(const float* Ab, const float* Bb,
                                        float* Dst, float scale, int ti4, int tj4) {
  float acc[4][4] = {};
#pragma unroll 8
  for (int kk = 0; kk < 64; ++kk) {
    f32x4 a = *(const f32x4*)&Ab[kk * 68 + ti4];
    f32x4 b = *(const f32x4*)&Bb[kk * 68 + tj4];
#pragma unroll
    for (int i = 0; i < 4; ++i)
#pragma unroll
      for (int j = 0; j < 4; ++j) acc[i][j] += a[i] * b[j];
  }
#pragma unroll
  for (int i = 0; i < 4; ++i) {
    f32x4 o = {acc[i][0] * scale, acc[i][1] * scale, acc[i][2] * scale, acc[i][3] * scale};
    *(f32x4*)&Dst[(ti4 + i) * 68 + tj4] = o;
  }
}

__device__ __forceinline__ void loadW(float* Bsh, const float* W, int ldw, int off, int tid) {
  for (int i = tid * 4; i < 4096; i += 1024) {
    int r = i >> 6, c = i & 63;
    *(f32x4*)&Bsh[r * 68 + c] = *(const f32x4*)&W[r * ldw + off + c];
  }
}

__global__ __launch_bounds__(256) void fuse_kernel(const float* __restrict__ G,
                                                   const float* __restrict__ Wqkv,
                                                   const float* __restrict__ Wproj,
                                                   unsigned short* __restrict__ Fpk) {
  __shared__ __align__(16) float A[64 * 68];
  __shared__ __align__(16) float B[64 * 68];
  __shared__ __align__(16) float T[64 * 68];
  const int tid = threadIdx.x;
  const int bn = blockIdx.x;
  const int ti4 = (tid >> 4) * 4, tj4 = (tid & 15) * 4;

  // load compact G -> A ; Wk -> B (both vectorized)
  for (int i = tid * 4; i < 4096; i += 1024) {
    int r = i >> 6, c = i & 63;
    *(f32x4*)&A[r * 68 + c] = *(const f32x4*)&G[bn * 4096 + i];
    *(f32x4*)&B[r * 68 + c] = *(const f32x4*)&Wqkv[r * 192 + 64 + c];
  }
  __syncthreads();
  // T1[f][d] = sum_g G[f][g] Wk[g][d] ; G symmetric -> read A[kk][row]
  mm_colA(A, B, T, 1.f, ti4, tj4);
  __syncthreads();
  loadW(B, Wqkv, 192, 0, tid);  // Wq
  __syncthreads();
  // S[c][d] = temp * sum_f Wq[f][c] T1[f][d]  -> A
  mm_colA(B, T, A, 0.125f, ti4, tj4);
  __syncthreads();
  // softmax rows of A (over d): 4 lanes per row
  {
    const int row = tid >> 2, q = tid & 3;
    float* Ar = A + row * 68 + q * 16;
    f32x4 v[4];
#pragma unroll
    for (int t = 0; t < 4; ++t) v[t] = *(const f32x4*)&Ar[t * 4];
    float mx = -1e30f;
#pragma unroll
    for (int t = 0; t < 4; ++t)
#pragma unroll
      for (int e = 0; e < 4; ++e) mx = fmaxf(mx, v[t][e]);
    mx = fmaxf(mx, __shfl_xor(mx, 1));
    mx = fmaxf(mx, __shfl_xor(mx, 2));
    float s = 0.f;
#pragma unroll
    for (int t = 0; t < 4; ++t)
#pragma unroll
      for (int e = 0; e < 4; ++e) {
        float ev = __expf(v[t][e] - mx);
        v[t][e] = ev;
        s += ev;
      }
    s += __shfl_xor(s, 1);
    s += __shfl_xor(s, 2);
    float inv = 1.f / s;
#pragma unroll
    for (int t = 0; t < 4; ++t) {
      v[t] *= inv;
      *(f32x4*)&Ar[t * 4] = v[t];
    }
  }
  __syncthreads();
  loadW(B, Wproj, 64, 0, tid);
  __syncthreads();
  // T2[d][e] = sum_c W[c][d] Wproj[c][e]  -> T
  mm_colA(A, B, T, 1.f, ti4, tj4);
  __syncthreads();
  loadW(B, Wqkv, 192, 128, tid);  // Wv
  __syncthreads();
  // F[f][e] = sum_d Wv[f][d] T2[d][e]; emit transposed bf16 hi/lo planes:
  // Fpk[bn][0][e*64+f] = hi, Fpk[bn][1][e*64+f] = lo
  {
    float acc[4][4] = {};
#pragma unroll 2
    for (int kk0 = 0; kk0 < 64; kk0 += 4) {
      f32x4 a4[4], b4[4];
#pragma unroll
      for (int i = 0; i < 4; ++i) a4[i] = *(const f32x4*)&B[(ti4 + i) * 68 + kk0];
#pragma unroll
      for (int kx = 0; kx < 4; ++kx) b4[kx] = *(const f32x4*)&T[(kk0 + kx) * 68 + tj4];
#pragma unroll
      for (int kx = 0; kx < 4; ++kx)
#pragma unroll
        for (int i = 0; i < 4; ++i)
#pragma unroll
          for (int j = 0; j < 4; ++j) acc[i][j] += a4[i][kx] * b4[kx][j];
    }
    unsigned short* fp = Fpk + (size_t)bn * 8192;
#pragma unroll
    for (int j = 0; j < 4; ++j) {
      u16x4 hv, lv;
#pragma unroll
      for (int i = 0; i < 4; ++i) {
        unsigned short hb = f2bf(acc[i][j]);
        hv[i] = hb;
        lv[i] = f2bf(acc[i][j] - bf2f(hb));
      }
      *(u16x4*)&fp[(tj4 + j) * 64 + ti4] = hv;
      *(u16x4*)&fp[4096 + (tj4 + j) * 64 + ti4] = lv;
    }
  }
}

// ---------------------------------------------------------------------------
// Kernel C: out[pixel][e] = sum_f x[pixel][f] * F[bn(pixel)][f][e]
// F-frags load directly from pre-converted bf16 planes (1 b128 load each).
// Operand-swapped MFMA: D[e][pixel] -> f32x4 nontemporal stores.
// ---------------------------------------------------------------------------
__global__ __launch_bounds__(256) void out_kernel(const float* __restrict__ x,
                                                  const unsigned short* __restrict__ Fpk,
                                                  float* __restrict__ out) {
  const int tid = threadIdx.x;
  const int lane = tid & 63;
  const int wave = tid >> 6;
  const int blk = blockIdx.x;
  const int hyg = blk & 63;
  const int bn = blk >> 6;
  const int b = bn >> 2;
  const int m1 = (bn >> 1) & 1;
  const int m2 = bn & 1;

  // F-frags from packed planes: Ft[e][k] bf16, hi and lo
  s16x8 bh[2][4], bl[2][4];
  {
    const unsigned short* fph = Fpk + (size_t)bn * 8192;
    const unsigned short* fpl = fph + 4096;
    const int e15 = lane & 15;
    const int k0b = (lane >> 4) * 8;
#pragma unroll
    for (int ksj = 0; ksj < 2; ++ksj)
#pragma unroll
      for (int tc = 0; tc < 4; ++tc) {
        int off = (tc * 16 + e15) * 64 + ksj * 32 + k0b;
        bh[ksj][tc] = *(const s16x8*)&fph[off];
        bl[ksj][tc] = *(const s16x8*)&fpl[off];
      }
  }

  const int e4 = (lane >> 4) * 4;  // acc rows: 4 consecutive e within tc-tile

  for (int r = 0; r < 2; ++r) {
    int hy = hyg * 2 + r;
    int y = 2 * hy + m1;
    const float* xrow = x + ((b * 256 + y) * 256) * 64;
    float* orow = out + ((b * 256 + y) * 256) * 64;
#pragma unroll
    for (int ptI = 0; ptI < 2; ++ptI) {
      int pt = wave + ptI * 4;  // px-tile 0..7
      int wx = pt * 16 + (lane & 15);
      int xx = 2 * wx + m2;
      const float* pp = xrow + xx * 64 + (lane >> 4) * 8;
      s16x8 ah[2], al[2];
#pragma unroll
      for (int ksj = 0; ksj < 2; ++ksj) {
        f32x4 u0 = *(const f32x4*)(pp + ksj * 32);
        f32x4 u1 = *(const f32x4*)(pp + ksj * 32 + 4);
        s16x8 hv, lv;
#pragma unroll
        for (int j = 0; j < 4; ++j) {
          unsigned short hb0 = f2bf(u0[j]);
          unsigned short hb1 = f2bf(u1[j]);
          hv[j] = (short)hb0;
          hv[4 + j] = (short)hb1;
          lv[j] = (short)f2bf(u0[j] - bf2f(hb0));
          lv[4 + j] = (short)f2bf(u1[j] - bf2f(hb1));
        }
        ah[ksj] = hv;
        al[ksj] = lv;
      }
      f32x4 acc[4];
#pragma unroll
      for (int tc = 0; tc < 4; ++tc) acc[tc] = (f32x4){0.f, 0.f, 0.f, 0.f};
#pragma unroll
      for (int ksj = 0; ksj < 2; ++ksj)
#pragma unroll
        for (int tc = 0; tc < 4; ++tc) {
          bf16x8 A_h = __builtin_bit_cast(bf16x8, ah[ksj]);
          bf16x8 A_l = __builtin_bit_cast(bf16x8, al[ksj]);
          bf16x8 B_h = __builtin_bit_cast(bf16x8, bh[ksj][tc]);
          bf16x8 B_l = __builtin_bit_cast(bf16x8, bl[ksj][tc]);
          // swapped: D[row=e][col=pixel]
          acc[tc] = __builtin_amdgcn_mfma_f32_16x16x32_bf16(B_h, A_h, acc[tc], 0, 0, 0);
          acc[tc] = __builtin_amdgcn_mfma_f32_16x16x32_bf16(B_l, A_h, acc[tc], 0, 0, 0);
          acc[tc] = __builtin_amdgcn_mfma_f32_16x16x32_bf16(B_h, A_l, acc[tc], 0, 0, 0);
        }
      // lane's column = its own wx; rows = e = tc*16 + e4 + 0..3
      float* op = orow + xx * 64;
#pragma unroll
      for (int tc = 0; tc < 4; ++tc) {
        __builtin_nontemporal_store(acc[tc], (f32x4*)&op[tc * 16 + e4]);
      }
    }
  }
}

extern "C" void kernel_launch(void* const* d_in, const int* in_sizes, int n_in,
                              void* d_out, int out_size, void* d_ws, size_t ws_size,
                              hipStream_t stream) {
  (void)in_sizes; (void)n_in; (void)out_size; (void)ws_size;
  const float* x = (const float*)d_in[0];
  const float* Wqkv = (const float*)d_in[1];
  const float* Wproj = (const float*)d_in[2];
  float* out = (float*)d_out;

  // workspace: Gpart = 32*NCH*4096 f32 (16.8 MB), G = 32*4096 f32 (512 KB),
  //            Fpk = 32*8192 u16 (512 KB). ws_size is >=512 MB (fill evidence).
  float* Gpart = (float*)d_ws;
  float* G = Gpart + (size_t)32 * NCH * 4096;
  unsigned short* Fpk = (unsigned short*)(G + 32 * 4096);

  gram_kernel<<<32 * NCH, 256, 0, stream>>>(x, Gpart);
  reduce_kernel<<<256, 256, 0, stream>>>(Gpart, G);
  fuse_kernel<<<32, 256, 0, stream>>>(G, Wqkv, Wproj, Fpk);
  out_kernel<<<2048, 256, 0, stream>>>(x, Fpk, out);
}